// Round 10
// baseline (204.672 us; speedup 1.0000x reference)
//
#include <hip/hip_runtime.h>
#include <math.h>

#define NROW 64
#define DIM  131072

// ---------------- complex helpers ----------------
struct cf { float x, y; };
__device__ __forceinline__ cf cadd(cf a, cf b){ return {a.x+b.x, a.y+b.y}; }
__device__ __forceinline__ cf csub(cf a, cf b){ return {a.x-b.x, a.y-b.y}; }
__device__ __forceinline__ cf cmul(cf a, cf b){ return {a.x*b.x - a.y*b.y, a.x*b.y + a.y*b.x}; }
template<int SG> __device__ __forceinline__ cf muli(cf a){
  return (SG > 0) ? cf{-a.y, a.x} : cf{a.y, -a.x};
}
__device__ __forceinline__ float sigmoidf(float x){ return 1.0f/(1.0f + __expf(-x)); }

// wave-local fence: one 64-lane wave exchanging via LDS. DS ops of a wave are
// processed in program order; this only stops compiler reordering.
__device__ __forceinline__ void wsync(){
  __builtin_amdgcn_wave_barrier();
  asm volatile("" ::: "memory");
}

typedef float __attribute__((ext_vector_type(4))) fvec4;

template<int SG> __device__ __forceinline__ void fft4(cf&a0, cf&a1, cf&a2, cf&a3){
  cf e0=cadd(a0,a2), e1=csub(a0,a2), o0=cadd(a1,a3), o1=csub(a1,a3);
  cf w=muli<SG>(o1);
  a0=cadd(e0,o0); a2=csub(e0,o0); a1=cadd(e1,w); a3=csub(e1,w);
}

template<int SG> __device__ __forceinline__ void fft8(cf v[8]){
  cf e0=v[0], e1=v[2], e2=v[4], e3=v[6];
  cf o0=v[1], o1=v[3], o2=v[5], o3=v[7];
  fft4<SG>(e0,e1,e2,e3); fft4<SG>(o0,o1,o2,o3);
  const float R=0.70710678118654752f;
  cf w1=cmul(o1, cf{R, (float)SG*R});
  cf w2=muli<SG>(o2);
  cf w3=cmul(o3, cf{-R, (float)SG*R});
  v[0]=cadd(e0,o0); v[4]=csub(e0,o0);
  v[1]=cadd(e1,w1); v[5]=csub(e1,w1);
  v[2]=cadd(e2,w2); v[6]=csub(e2,w2);
  v[3]=cadd(e3,w3); v[7]=csub(e3,w3);
}

template<int SG> __device__ __forceinline__ void fft16(cf v[16]){
  cf e[8], o[8];
  #pragma unroll
  for(int i=0;i<8;i++){ e[i]=v[2*i]; o[i]=v[2*i+1]; }
  fft8<SG>(e); fft8<SG>(o);
  const float C[8]={1.f,0.92387953251128674f,0.70710678118654752f,0.38268343236508977f,
                    0.f,-0.38268343236508977f,-0.70710678118654752f,-0.92387953251128674f};
  const float S[8]={0.f,0.38268343236508977f,0.70710678118654752f,0.92387953251128674f,
                    1.f,0.92387953251128674f,0.70710678118654752f,0.38268343236508977f};
  #pragma unroll
  for(int k=0;k<8;k++){
    cf w=cmul(o[k], cf{C[k], (float)SG*S[k]});
    v[k]=cadd(e[k],w); v[k+8]=csub(e[k],w);
  }
}

// ---------------- K1: per-block max|z| (no atomics, no init) + output tail ----------------
__global__ __launch_bounds__(256) void k1_maxabs(
    const float* __restrict__ z, float* __restrict__ wsmax,
    float* __restrict__ dout, int cplx)
{
  __shared__ float red[256];
  int t = threadIdx.x, bid = blockIdx.x;
  size_t i0 = (size_t)bid*blockDim.x + t;
  size_t stride = (size_t)gridDim.x*blockDim.x;
  const float4* z4 = (const float4*)z;
  size_t n4 = (size_t)NROW*DIM/4;
  float m = 0.f;
  for(size_t i=i0;i<n4;i+=stride){
    float4 v=z4[i];
    m = fmaxf(m, fmaxf(fmaxf(fabsf(v.x),fabsf(v.y)), fmaxf(fabsf(v.z),fabsf(v.w))));
  }
  red[t]=m; __syncthreads();
  #pragma unroll
  for(int s=128;s>0;s>>=1){
    if(t<(unsigned)s) red[t]=fmaxf(red[t],red[t+s]);
    __syncthreads();
  }
  if(t==0) wsmax[bid]=red[0];       // unconditional per-block slot: no init required
  if(bid==0){                        // folded former k0_tail
    size_t base = (size_t)2*NROW*DIM*cplx;
    if(t < NROW) dout[base + t] = 0.f;
    else if(t == NROW) dout[base + NROW] = 1.0f;
  }
}

// ---------------- K2: forward stage-1 (FFT-256 over n2) + new_trace ----------------
// Two tiles per block (same row, adjacent n1 chunks): amortizes the s-reduce,
// twiddle fill, and launch ramp; adjacent chunks improve L2 locality.
__global__ __launch_bounds__(256) void k2_fwd1(
    const float* __restrict__ z, const float* __restrict__ tr,
    const float* __restrict__ ctrl, const float* __restrict__ wsmax,
    float2* __restrict__ Bws, float* __restrict__ out_nt, int cplx)
{
  __shared__ float reb[4384], imb[4384];
  __shared__ float twc[256], tws[256];
  int t = threadIdx.x;
  int tile0 = blockIdx.x << 1;
  int b = tile0 >> 5;                  // both tiles in the same row
  {
    float sv, cv;
    __sincosf(-0.0245436926061703f * (float)t, &sv, &cv); // -2*pi/256 * t
    twc[t]=cv; tws[t]=sv;
  }
  // inline reduction of K1's 1024 per-block maxima (4 KB, L2-hit) -> s
  float s;
  {
    const float4* w4 = (const float4*)wsmax;
    float4 v = w4[t];               // 256 threads x float4 = 1024 floats
    reb[t] = fmaxf(fmaxf(v.x,v.y), fmaxf(v.z,v.w));
    __syncthreads();
    #pragma unroll
    for(int st=128; st>0; st>>=1){
      if(t<(unsigned)st) reb[t]=fmaxf(reb[t],reb[t+st]);
      __syncthreads();
    }
    s = 1.0f/(reb[0] + 1e-6f);
    __syncthreads();                // broadcast read done before reb reuse
  }
  float gs = sigmoidf(ctrl[b*3+0]);
  float cc = gs*s;
  const float4* zr4 = (const float4*)(z  + (size_t)b*DIM);
  const float4* tr4 = (const float4*)(tr + (size_t)b*DIM);

  for(int sub=0; sub<2; ++sub){
    int n1b = ((tile0 + sub) & 31) << 4;
    #pragma unroll
    for(int it=0; it<4; ++it){
      int e = t + 256*it;          // 0..1023
      int n2 = e >> 2, j4 = e & 3;
      int fi = n2*128 + (n1b>>2) + j4;
      float4 zv = zr4[fi];
      float4 tv = tr4[fi];
      int lb = n2*17 + j4*4;
      reb[lb+0]=zv.x; reb[lb+1]=zv.y; reb[lb+2]=zv.z; reb[lb+3]=zv.w;
      imb[lb+0]=tv.x; imb[lb+1]=tv.y; imb[lb+2]=tv.z; imb[lb+3]=tv.w;
      float n0 = fmaf(cc, zv.x, tv.x);
      float n1v= fmaf(cc, zv.y, tv.y);
      float n2v= fmaf(cc, zv.z, tv.z);
      float n3 = fmaf(cc, zv.w, tv.w);
      size_t n = (size_t)n2*512 + n1b + j4*4;
      size_t oidx = (size_t)b*DIM + n;
      if(cplx == 2){
        fvec4 a  = {n0, 0.f, n1v, 0.f};
        fvec4 bq = {n2v, 0.f, n3, 0.f};
        fvec4* op = (fvec4*)((float2*)out_nt + oidx);
        __builtin_nontemporal_store(a,  op);
        __builtin_nontemporal_store(bq, op+1);
      } else {
        out_nt[oidx+0]=n0; out_nt[oidx+1]=n1v; out_nt[oidx+2]=n2v; out_nt[oidx+3]=n3;
      }
    }
    __syncthreads();
    int f = t & 15, p = t >> 4;
    cf v[16];
    #pragma unroll
    for(int q=0;q<16;q++){ int n2=q*16+p; v[q].x=reb[n2*17+f]; v[q].y=imb[n2*17+f]; }
    fft16<-1>(v);
    #pragma unroll
    for(int kq=1;kq<16;kq++){ int tt=(p*kq)&255; v[kq]=cmul(v[kq], cf{twc[tt], tws[tt]}); }
    __syncthreads();
    #pragma unroll
    for(int kq=0;kq<16;kq++){ reb[f*274 + kq*17 + p]=v[kq].x; imb[f*274 + kq*17 + p]=v[kq].y; }
    __syncthreads();
    #pragma unroll
    for(int pp=0;pp<16;pp++){ v[pp].x=reb[f*274 + p*17 + pp]; v[pp].y=imb[f*274 + p*17 + pp]; }
    fft16<-1>(v);
    int nn1 = n1b + f;
    cf w, st;
    {
      float sv, cv;
      __sincosf(-4.793689960382698e-05f * (float)(nn1*p), &sv, &cv);
      w = {cv, sv};
      __sincosf(-4.793689960382698e-05f * 16.f * (float)nn1, &sv, &cv);
      st = {cv, sv};
    }
    #pragma unroll
    for(int kp=0;kp<16;kp++){
      int k2 = kp*16 + p;
      cf r = cmul(v[kp], w);
      Bws[((size_t)b<<17) + (size_t)k2*512 + nn1] = make_float2(r.x, r.y);
      w = cmul(w, st);
    }
    __syncthreads();   // all LDS reads done before next sub overwrites
  }
}

// ---------------- K3: row-pair packed inverse ----------------
// One wave per 512-column, in-place FFT (no T buffer); half twiddle table.
template<int SG>
__device__ __forceinline__ void fft512_wave(
    float* Cre, float* Cim, int lane, const float* twc, const float* tws)
{
  cf v[8];
  int kQ = lane>>3, pp = lane&7;
  #pragma unroll
  for(int q=0;q<8;q++){ v[q].x=Cre[q*64+lane]; v[q].y=Cim[q*64+lane]; }
  fft8<SG>(v);
  #pragma unroll
  for(int kq=1;kq<8;kq++){
    int tt=(lane*kq)&511; int ti=tt&255; float sg=(tt&256)?-1.f:1.f;
    v[kq]=cmul(v[kq], cf{sg*twc[ti], (float)SG*sg*tws[ti]});
  }
  wsync();
  #pragma unroll
  for(int kq=0;kq<8;kq++){ Cre[lane*9+kq]=v[kq].x; Cim[lane*9+kq]=v[kq].y; }
  wsync();
  #pragma unroll
  for(int q=0;q<8;q++){ int idx=(q*8+pp)*9+kQ; v[q].x=Cre[idx]; v[q].y=Cim[idx]; }
  fft8<SG>(v);
  #pragma unroll
  for(int kq=1;kq<8;kq++){
    int tt=(pp*kq*8)&511; int ti=tt&255; float sg=(tt&256)?-1.f:1.f;
    v[kq]=cmul(v[kq], cf{sg*twc[ti], (float)SG*sg*tws[ti]});
  }
  wsync();
  #pragma unroll
  for(int kq=0;kq<8;kq++){ Cre[pp*73+kq*9+kQ]=v[kq].x; Cim[pp*73+kq*9+kQ]=v[kq].y; }
  wsync();
  #pragma unroll
  for(int p2=0;p2<8;p2++){ int idx=p2*73 + kQ*9 + pp; v[p2].x=Cre[idx]; v[p2].y=Cim[idx]; }
  fft8<SG>(v);
  wsync();
  #pragma unroll
  for(int kp=0;kp<8;kp++){ int k=kp*64 + kQ*8 + pp; Cre[k]=v[kp].x; Cim[k]=v[kp].y; }
  wsync();
}

// Block = 2 waves; TWO (row-pair, col-pair) tiles processed sequentially.
// Each wave owns one column per tile; fwd FFT both rows -> Hermitian product ->
// combine G = R_b0 + i*R_b1 -> one inverse FFT-512 -> store to b0's slot.
__global__ __launch_bounds__(128) void k3_mid(
    float2* __restrict__ Bws, const float* __restrict__ ctrl,
    const float* __restrict__ wsmax)
{
  __shared__ float Cbuf[2][1168];          // per column: [re 584 | im 584]
  __shared__ float twc[256], tws[256];     // half table of W_512
  __shared__ float sred[128];
  int t = threadIdx.x;
  int bp = blockIdx.x >> 6;                // row pair 0..31
  int prb = (blockIdx.x & 63) << 1;        // pr base: 0,2,..,126
  int b0 = bp*2, b1 = b0+1;
  int col = t >> 6, lane = t & 63;
  for(int i=t;i<256;i+=128){
    float sv,cv; __sincosf(0.0122718463030851f*(float)i, &sv, &cv); // +2*pi/512
    twc[i]=cv; tws[i]=sv;
  }
  // inline reduce of K1 maxima (1024 floats, L2-hit)
  float s;
  {
    const float4* w4 = (const float4*)wsmax;
    float4 a = w4[t];          // 128 threads x 2 float4
    float4 bq = w4[t+128];
    float m = fmaxf(fmaxf(fmaxf(a.x,a.y),fmaxf(a.z,a.w)),
                    fmaxf(fmaxf(bq.x,bq.y),fmaxf(bq.z,bq.w)));
    sred[t]=m; __syncthreads();
    #pragma unroll
    for(int st=64; st>0; st>>=1){
      if(t<(unsigned)st) sred[t]=fmaxf(sred[t],sred[t+st]);
      __syncthreads();
    }
    s = 1.0f/(sred[0] + 1e-6f);
  }
  float gs0 = sigmoidf(ctrl[b0*3+0]);
  float al0 = sigmoidf(ctrl[b0*3+1]) * (1.0f/(float)DIM);
  float gs1 = sigmoidf(ctrl[b1*3+0]);
  float al1 = sigmoidf(ctrl[b1*3+1]) * (1.0f/(float)DIM);
  float* Cre = Cbuf[col]; float* Cim = Cre + 584;

  for(int sub=0; sub<2; ++sub){
    int pr = prb + sub;
    int cA = (pr==0) ? 0   : pr;
    int cB = (pr==0) ? 128 : 256-pr;
    int myc = col ? cB : cA;
    const float* Pre = (pr==0) ? Cre : Cbuf[1-col];
    const float* Pim = Pre + 584;
    float2* colp0 = Bws + ((size_t)b0<<17) + ((size_t)myc<<9);
    float2* colp1 = Bws + ((size_t)b1<<17) + ((size_t)myc<<9);
    cf pv0[8], pv1[8];

    // row b0: forward + Hermitian product
    {
      const float4* c4 = (const float4*)colp0;
      #pragma unroll
      for(int r=0;r<4;r++){
        float4 q = c4[lane + 64*r];
        int j = 2*(lane + 64*r);
        Cre[j]=q.x;   Cim[j]=q.y;
        Cre[j+1]=q.z; Cim[j+1]=q.w;
      }
    }
    __syncthreads();   // twiddles (sub 0) + both columns loaded
    fft512_wave<-1>(Cre, Cim, lane, twc, tws);
    __syncthreads();   // partner spectrum ready
    #pragma unroll
    for(int rr=0;rr<8;rr++){
      int k1  = lane + 64*rr;
      int k1p = (myc==0) ? ((512-k1)&511) : (511-k1);
      float cr = Cre[k1], ci = Cim[k1];
      float qr = Pre[k1p], qi = -Pim[k1p];          // conj(C[N-k])
      float zur = 0.5f*(cr+qr), zui = 0.5f*(ci+qi);
      float dr = cr-qr, di = ci-qi;
      float tfr = 0.5f*di, tfi = -0.5f*dr;
      float szr = s*zur, szi = s*zui;
      float ntr = fmaf(gs0, szr, tfr), nti = fmaf(gs0, szi, tfi);
      pv0[rr].x = (ntr*szr + nti*szi)*al0;
      pv0[rr].y = (nti*szr - ntr*szi)*al0;
    }
    __syncthreads();   // b0 reads complete before overwrite

    // row b1: forward + Hermitian product
    {
      const float4* c4 = (const float4*)colp1;
      #pragma unroll
      for(int r=0;r<4;r++){
        float4 q = c4[lane + 64*r];
        int j = 2*(lane + 64*r);
        Cre[j]=q.x;   Cim[j]=q.y;
        Cre[j+1]=q.z; Cim[j+1]=q.w;
      }
    }
    wsync();
    fft512_wave<-1>(Cre, Cim, lane, twc, tws);
    __syncthreads();   // partner b1 spectrum ready
    #pragma unroll
    for(int rr=0;rr<8;rr++){
      int k1  = lane + 64*rr;
      int k1p = (myc==0) ? ((512-k1)&511) : (511-k1);
      float cr = Cre[k1], ci = Cim[k1];
      float qr = Pre[k1p], qi = -Pim[k1p];
      float zur = 0.5f*(cr+qr), zui = 0.5f*(ci+qi);
      float dr = cr-qr, di = ci-qi;
      float tfr = 0.5f*di, tfi = -0.5f*dr;
      float szr = s*zur, szi = s*zui;
      float ntr = fmaf(gs1, szr, tfr), nti = fmaf(gs1, szi, tfi);
      pv1[rr].x = (ntr*szr + nti*szi)*al1;
      pv1[rr].y = (nti*szr - ntr*szi)*al1;
    }
    __syncthreads();   // b1 reads complete before overwrite

    // combine G = R_b0 + i*R_b1, one inverse FFT-512
    #pragma unroll
    for(int rr=0;rr<8;rr++){
      int k1 = lane + 64*rr;
      Cre[k1] = pv0[rr].x - pv1[rr].y;
      Cim[k1] = pv0[rr].y + pv1[rr].x;
    }
    wsync();           // own-wave write->read ordering
    fft512_wave<1>(Cre, Cim, lane, twc, tws);
    cf w, st;
    {
      float sv,cv;
      __sincosf(4.793689960382698e-05f * (float)(lane*myc), &sv, &cv);
      w = {cv, sv};
      __sincosf(4.793689960382698e-05f * 64.f * (float)myc, &sv, &cv);
      st = {cv, sv};
    }
    #pragma unroll
    for(int rr=0;rr<8;rr++){
      int m1 = lane + 64*rr;
      cf r2 = cmul(cf{Cre[m1],Cim[m1]}, w);
      colp0[m1] = make_float2(r2.x, r2.y);
      w = cmul(w, st);
    }
    // no block barrier needed here: remaining cross-wave reads in the next sub
    // are fenced by that sub's own __syncthreads() calls; buffers are per-wave.
  }
}

// ---------------- K4: inverse stage-2 (IFFT-256 over k2), writes TWO rows ----------------
// Two m1-tiles per block (same row-pair): amortizes twiddle fill + ramp.
__global__ __launch_bounds__(256) void k4_inv2(
    const float2* __restrict__ Qws, float* __restrict__ dout, int cplx)
{
  __shared__ float reb[4384], imb[4384];
  __shared__ float twc[256], tws[256];
  int t = threadIdx.x;
  int r0 = blockIdx.x << 1;
  int bp = r0 >> 5;                         // row pair (same for both tiles)
  int b0 = bp*2;
  {
    float sv, cv;
    __sincosf(0.0245436926061703f * (float)t, &sv, &cv); // +2*pi/256 * t
    twc[t]=cv; tws[t]=sv;
  }
  const float4* Qp = (const float4*)(Qws + ((size_t)b0<<17));

  for(int sub=0; sub<2; ++sub){
    int m1b = ((r0 + sub) & 31) << 4;
    #pragma unroll
    for(int it=0; it<8; ++it){
      int e = t + 256*it;
      int k2 = e >> 3, j = e & 7;
      float4 q = Qp[k2*256 + (m1b>>1) + j];
      int lb = k2*17 + 2*j;
      reb[lb+0]=q.x; imb[lb+0]=q.y;
      reb[lb+1]=q.z; imb[lb+1]=q.w;
    }
    __syncthreads();
    int f = t & 15, p = t >> 4;
    cf v[16];
    #pragma unroll
    for(int q=0;q<16;q++){ int k2=q*16+p; v[q].x=reb[k2*17+f]; v[q].y=imb[k2*17+f]; }
    fft16<1>(v);
    #pragma unroll
    for(int kq=1;kq<16;kq++){ int tt=(p*kq)&255; v[kq]=cmul(v[kq], cf{twc[tt], tws[tt]}); }
    __syncthreads();
    #pragma unroll
    for(int kq=0;kq<16;kq++){ reb[f*274+kq*17+p]=v[kq].x; imb[f*274+kq*17+p]=v[kq].y; }
    __syncthreads();
    #pragma unroll
    for(int pp=0;pp<16;pp++){ v[pp].x=reb[f*274+p*17+pp]; v[pp].y=imb[f*274+p*17+pp]; }
    fft16<1>(v);
    #pragma unroll
    for(int kp=0;kp<16;kp++){
      int m2 = kp*16 + p;
      size_t n = (size_t)(m1b + f) + (size_t)512*m2;
      size_t o0 = (size_t)b0*DIM + n;        // y.x -> read[b0], y.y -> read[b0+1]
      if(cplx==2){
        ((float2*)dout)[o0]       = make_float2(v[kp].x, 0.f);
        ((float2*)dout)[o0 + DIM] = make_float2(v[kp].y, 0.f);
      } else {
        dout[o0]       = v[kp].x;
        dout[o0 + DIM] = v[kp].y;
      }
    }
    __syncthreads();   // all LDS reads done before next sub overwrites
  }
}

// ---------------- launch: 4 nodes ----------------
extern "C" void kernel_launch(void* const* d_in, const int* in_sizes, int n_in,
                              void* d_out, int out_size, void* d_ws, size_t ws_size,
                              hipStream_t stream)
{
  (void)in_sizes; (void)n_in; (void)ws_size;
  const float* z    = (const float*)d_in[0];
  const float* tr   = (const float*)d_in[1];
  const float* ctrl = (const float*)d_in[2];
  float* dout = (float*)d_out;
  // complex64 outputs flattened as interleaved float32 -> out_size = 2*2*B*DIM + B + 1.
  int cplx = (out_size > 20000000) ? 2 : 1;
  float* wsmax = (float*)d_ws;                   // 1024 per-block max slots
  float2* Bws = (float2*)((char*)d_ws + 8192);   // 64 MiB intermediate, in-place through K3

  hipLaunchKernelGGL(k1_maxabs,dim3(1024), dim3(256), 0, stream, z, wsmax, dout, cplx);
  hipLaunchKernelGGL(k2_fwd1,  dim3(1024), dim3(256), 0, stream,
                     z, tr, ctrl, wsmax, Bws, dout + (size_t)NROW*DIM*cplx, cplx);
  hipLaunchKernelGGL(k3_mid,   dim3(2048), dim3(128), 0, stream, Bws, ctrl, wsmax);
  hipLaunchKernelGGL(k4_inv2,  dim3(512),  dim3(256), 0, stream, Bws, dout, cplx);
}

// Round 11
// 193.291 us; speedup vs baseline: 1.0589x; 1.0589x over previous
//
#include <hip/hip_runtime.h>
#include <math.h>

#define NROW 64
#define DIM  131072

// ---------------- complex helpers ----------------
struct cf { float x, y; };
__device__ __forceinline__ cf cadd(cf a, cf b){ return {a.x+b.x, a.y+b.y}; }
__device__ __forceinline__ cf csub(cf a, cf b){ return {a.x-b.x, a.y-b.y}; }
__device__ __forceinline__ cf cmul(cf a, cf b){ return {a.x*b.x - a.y*b.y, a.x*b.y + a.y*b.x}; }
template<int SG> __device__ __forceinline__ cf muli(cf a){
  return (SG > 0) ? cf{-a.y, a.x} : cf{a.y, -a.x};
}
__device__ __forceinline__ float sigmoidf(float x){ return 1.0f/(1.0f + __expf(-x)); }

// wave-local fence: one 64-lane wave exchanging via LDS. DS ops of a wave are
// processed in program order; this only stops compiler reordering.
__device__ __forceinline__ void wsync(){
  __builtin_amdgcn_wave_barrier();
  asm volatile("" ::: "memory");
}

typedef float __attribute__((ext_vector_type(4))) fvec4;

template<int SG> __device__ __forceinline__ void fft4(cf&a0, cf&a1, cf&a2, cf&a3){
  cf e0=cadd(a0,a2), e1=csub(a0,a2), o0=cadd(a1,a3), o1=csub(a1,a3);
  cf w=muli<SG>(o1);
  a0=cadd(e0,o0); a2=csub(e0,o0); a1=cadd(e1,w); a3=csub(e1,w);
}

template<int SG> __device__ __forceinline__ void fft8(cf v[8]){
  cf e0=v[0], e1=v[2], e2=v[4], e3=v[6];
  cf o0=v[1], o1=v[3], o2=v[5], o3=v[7];
  fft4<SG>(e0,e1,e2,e3); fft4<SG>(o0,o1,o2,o3);
  const float R=0.70710678118654752f;
  cf w1=cmul(o1, cf{R, (float)SG*R});
  cf w2=muli<SG>(o2);
  cf w3=cmul(o3, cf{-R, (float)SG*R});
  v[0]=cadd(e0,o0); v[4]=csub(e0,o0);
  v[1]=cadd(e1,w1); v[5]=csub(e1,w1);
  v[2]=cadd(e2,w2); v[6]=csub(e2,w2);
  v[3]=cadd(e3,w3); v[7]=csub(e3,w3);
}

template<int SG> __device__ __forceinline__ void fft16(cf v[16]){
  cf e[8], o[8];
  #pragma unroll
  for(int i=0;i<8;i++){ e[i]=v[2*i]; o[i]=v[2*i+1]; }
  fft8<SG>(e); fft8<SG>(o);
  const float C[8]={1.f,0.92387953251128674f,0.70710678118654752f,0.38268343236508977f,
                    0.f,-0.38268343236508977f,-0.70710678118654752f,-0.92387953251128674f};
  const float S[8]={0.f,0.38268343236508977f,0.70710678118654752f,0.92387953251128674f,
                    1.f,0.92387953251128674f,0.70710678118654752f,0.38268343236508977f};
  #pragma unroll
  for(int k=0;k<8;k++){
    cf w=cmul(o[k], cf{C[k], (float)SG*S[k]});
    v[k]=cadd(e[k],w); v[k+8]=csub(e[k],w);
  }
}

// ---------------- K1: per-block max|z| (no atomics, no init) + output tail ----------------
__global__ __launch_bounds__(256) void k1_maxabs(
    const float* __restrict__ z, float* __restrict__ wsmax,
    float* __restrict__ dout, int cplx)
{
  __shared__ float red[256];
  int t = threadIdx.x, bid = blockIdx.x;
  size_t i0 = (size_t)bid*blockDim.x + t;
  size_t stride = (size_t)gridDim.x*blockDim.x;
  const float4* z4 = (const float4*)z;
  size_t n4 = (size_t)NROW*DIM/4;
  float m = 0.f;
  for(size_t i=i0;i<n4;i+=stride){
    float4 v=z4[i];
    m = fmaxf(m, fmaxf(fmaxf(fabsf(v.x),fabsf(v.y)), fmaxf(fabsf(v.z),fabsf(v.w))));
  }
  red[t]=m; __syncthreads();
  #pragma unroll
  for(int s=128;s>0;s>>=1){
    if(t<(unsigned)s) red[t]=fmaxf(red[t],red[t+s]);
    __syncthreads();
  }
  if(t==0) wsmax[bid]=red[0];       // unconditional per-block slot: no init required
  if(bid==0){                        // folded former k0_tail
    size_t base = (size_t)2*NROW*DIM*cplx;
    if(t < NROW) dout[base + t] = 0.f;
    else if(t == NROW) dout[base + NROW] = 1.0f;
  }
}

// ---------------- K2: forward stage-1 (FFT-256 over n2) + new_trace ----------------
// n = n2*512 + n1. For fixed n1: B[k2][n1] = W_N^{n1*k2} * sum_{n2} c[n2*512+n1] W_256^{n2*k2}
// c = z + i*trace (unnormalized z; scale applied in K3).
__global__ __launch_bounds__(256) void k2_fwd1(
    const float* __restrict__ z, const float* __restrict__ tr,
    const float* __restrict__ ctrl, const float* __restrict__ wsmax,
    float2* __restrict__ Bws, float* __restrict__ out_nt, int cplx)
{
  __shared__ float reb[4384], imb[4384];
  __shared__ float twc[256], tws[256];
  int t = threadIdx.x;
  int b = blockIdx.x >> 5;
  int n1b = (blockIdx.x & 31) << 4;
  {
    float sv, cv;
    __sincosf(-0.0245436926061703f * (float)t, &sv, &cv); // -2*pi/256 * t
    twc[t]=cv; tws[t]=sv;
  }
  // inline reduction of K1's 1024 per-block maxima (4 KB, L2-hit) -> s
  float s;
  {
    const float4* w4 = (const float4*)wsmax;
    float4 v = w4[t];               // 256 threads x float4 = 1024 floats
    reb[t] = fmaxf(fmaxf(v.x,v.y), fmaxf(v.z,v.w));
    __syncthreads();
    #pragma unroll
    for(int st=128; st>0; st>>=1){
      if(t<(unsigned)st) reb[t]=fmaxf(reb[t],reb[t+st]);
      __syncthreads();
    }
    s = 1.0f/(reb[0] + 1e-6f);
    __syncthreads();                // broadcast read done before reb reuse
  }
  float gs = sigmoidf(ctrl[b*3+0]);
  float cc = gs*s;
  const float4* zr4 = (const float4*)(z  + (size_t)b*DIM);
  const float4* tr4 = (const float4*)(tr + (size_t)b*DIM);
  #pragma unroll
  for(int it=0; it<4; ++it){
    int e = t + 256*it;          // 0..1023
    int n2 = e >> 2, j4 = e & 3;
    int fi = n2*128 + (n1b>>2) + j4;
    float4 zv = zr4[fi];
    float4 tv = tr4[fi];
    int lb = n2*17 + j4*4;
    reb[lb+0]=zv.x; reb[lb+1]=zv.y; reb[lb+2]=zv.z; reb[lb+3]=zv.w;
    imb[lb+0]=tv.x; imb[lb+1]=tv.y; imb[lb+2]=tv.z; imb[lb+3]=tv.w;
    float n0 = fmaf(cc, zv.x, tv.x);
    float n1v= fmaf(cc, zv.y, tv.y);
    float n2v= fmaf(cc, zv.z, tv.z);
    float n3 = fmaf(cc, zv.w, tv.w);
    size_t n = (size_t)n2*512 + n1b + j4*4;
    size_t oidx = (size_t)b*DIM + n;
    if(cplx == 2){
      fvec4 a  = {n0, 0.f, n1v, 0.f};
      fvec4 bq = {n2v, 0.f, n3, 0.f};
      fvec4* op = (fvec4*)((float2*)out_nt + oidx);
      __builtin_nontemporal_store(a,  op);
      __builtin_nontemporal_store(bq, op+1);
    } else {
      out_nt[oidx+0]=n0; out_nt[oidx+1]=n1v; out_nt[oidx+2]=n2v; out_nt[oidx+3]=n3;
    }
  }
  __syncthreads();
  int f = t & 15, p = t >> 4;
  cf v[16];
  #pragma unroll
  for(int q=0;q<16;q++){ int n2=q*16+p; v[q].x=reb[n2*17+f]; v[q].y=imb[n2*17+f]; }
  fft16<-1>(v);
  #pragma unroll
  for(int kq=1;kq<16;kq++){ int tt=(p*kq)&255; v[kq]=cmul(v[kq], cf{twc[tt], tws[tt]}); }
  __syncthreads();
  #pragma unroll
  for(int kq=0;kq<16;kq++){ reb[f*274 + kq*17 + p]=v[kq].x; imb[f*274 + kq*17 + p]=v[kq].y; }
  __syncthreads();
  #pragma unroll
  for(int pp=0;pp<16;pp++){ v[pp].x=reb[f*274 + p*17 + pp]; v[pp].y=imb[f*274 + p*17 + pp]; }
  fft16<-1>(v);
  int nn1 = n1b + f;
  cf w, st;
  {
    float sv, cv;
    __sincosf(-4.793689960382698e-05f * (float)(nn1*p), &sv, &cv);
    w = {cv, sv};
    __sincosf(-4.793689960382698e-05f * 16.f * (float)nn1, &sv, &cv);
    st = {cv, sv};
  }
  #pragma unroll
  for(int kp=0;kp<16;kp++){
    int k2 = kp*16 + p;
    cf r = cmul(v[kp], w);
    Bws[((size_t)b<<17) + (size_t)k2*512 + nn1] = make_float2(r.x, r.y);
    w = cmul(w, st);
  }
}

// ---------------- K3: row-pair packed inverse ----------------
// One wave per 512-column, in-place FFT (no T buffer); half twiddle table.
template<int SG>
__device__ __forceinline__ void fft512_wave(
    float* Cre, float* Cim, int lane, const float* twc, const float* tws)
{
  cf v[8];
  int kQ = lane>>3, pp = lane&7;
  #pragma unroll
  for(int q=0;q<8;q++){ v[q].x=Cre[q*64+lane]; v[q].y=Cim[q*64+lane]; }
  fft8<SG>(v);
  #pragma unroll
  for(int kq=1;kq<8;kq++){
    int tt=(lane*kq)&511; int ti=tt&255; float sg=(tt&256)?-1.f:1.f;
    v[kq]=cmul(v[kq], cf{sg*twc[ti], (float)SG*sg*tws[ti]});
  }
  wsync();
  #pragma unroll
  for(int kq=0;kq<8;kq++){ Cre[lane*9+kq]=v[kq].x; Cim[lane*9+kq]=v[kq].y; }
  wsync();
  #pragma unroll
  for(int q=0;q<8;q++){ int idx=(q*8+pp)*9+kQ; v[q].x=Cre[idx]; v[q].y=Cim[idx]; }
  fft8<SG>(v);
  #pragma unroll
  for(int kq=1;kq<8;kq++){
    int tt=(pp*kq*8)&511; int ti=tt&255; float sg=(tt&256)?-1.f:1.f;
    v[kq]=cmul(v[kq], cf{sg*twc[ti], (float)SG*sg*tws[ti]});
  }
  wsync();
  #pragma unroll
  for(int kq=0;kq<8;kq++){ Cre[pp*73+kq*9+kQ]=v[kq].x; Cim[pp*73+kq*9+kQ]=v[kq].y; }
  wsync();
  #pragma unroll
  for(int p2=0;p2<8;p2++){ int idx=p2*73 + kQ*9 + pp; v[p2].x=Cre[idx]; v[p2].y=Cim[idx]; }
  fft8<SG>(v);
  wsync();
  #pragma unroll
  for(int kp=0;kp<8;kp++){ int k=kp*64 + kQ*8 + pp; Cre[k]=v[kp].x; Cim[k]=v[kp].y; }
  wsync();
}

// Block = 2 waves = one (row-pair, col-pair). Each wave owns one column and
// processes BOTH rows sequentially (fwd FFT + Hermitian product -> registers),
// then combines G = R_b0 + i*R_b1 in-register and runs ONE inverse FFT-512.
// Result stored to row b0's Bws slot; K4's complex output y = read_b0 + i*read_b1.
__global__ __launch_bounds__(128) void k3_mid(
    float2* __restrict__ Bws, const float* __restrict__ ctrl,
    const float* __restrict__ wsmax)
{
  __shared__ float Cbuf[2][1168];          // per column: [re 584 | im 584]
  __shared__ float twc[256], tws[256];     // half table of W_512
  __shared__ float sred[128];
  int t = threadIdx.x;
  int bp = blockIdx.x >> 7;                // row pair 0..31
  int pr = blockIdx.x & 127;
  int b0 = bp*2, b1 = b0+1;
  int cA = (pr==0) ? 0   : pr;
  int cB = (pr==0) ? 128 : 256-pr;
  int col = t >> 6, lane = t & 63;
  int myc = col ? cB : cA;
  for(int i=t;i<256;i+=128){
    float sv,cv; __sincosf(0.0122718463030851f*(float)i, &sv, &cv); // +2*pi/512
    twc[i]=cv; tws[i]=sv;
  }
  // inline reduce of K1 maxima (1024 floats, L2-hit)
  float s;
  {
    const float4* w4 = (const float4*)wsmax;
    float4 a = w4[t];          // 128 threads x 2 float4
    float4 bq = w4[t+128];
    float m = fmaxf(fmaxf(fmaxf(a.x,a.y),fmaxf(a.z,a.w)),
                    fmaxf(fmaxf(bq.x,bq.y),fmaxf(bq.z,bq.w)));
    sred[t]=m; __syncthreads();
    #pragma unroll
    for(int st=64; st>0; st>>=1){
      if(t<(unsigned)st) sred[t]=fmaxf(sred[t],sred[t+st]);
      __syncthreads();
    }
    s = 1.0f/(sred[0] + 1e-6f);
  }
  float gs0 = sigmoidf(ctrl[b0*3+0]);
  float al0 = sigmoidf(ctrl[b0*3+1]) * (1.0f/(float)DIM);
  float gs1 = sigmoidf(ctrl[b1*3+0]);
  float al1 = sigmoidf(ctrl[b1*3+1]) * (1.0f/(float)DIM);
  float* Cre = Cbuf[col]; float* Cim = Cre + 584;
  const float* Pre = (pr==0) ? Cre : Cbuf[1-col];
  const float* Pim = Pre + 584;
  float2* colp0 = Bws + ((size_t)b0<<17) + ((size_t)myc<<9);
  float2* colp1 = Bws + ((size_t)b1<<17) + ((size_t)myc<<9);
  cf pv0[8], pv1[8];

  // row b0: forward + Hermitian product
  {
    const float4* c4 = (const float4*)colp0;
    #pragma unroll
    for(int r=0;r<4;r++){
      float4 q = c4[lane + 64*r];
      int j = 2*(lane + 64*r);
      Cre[j]=q.x;   Cim[j]=q.y;
      Cre[j+1]=q.z; Cim[j+1]=q.w;
    }
  }
  __syncthreads();   // twiddles + both columns loaded
  fft512_wave<-1>(Cre, Cim, lane, twc, tws);
  __syncthreads();   // partner spectrum ready
  #pragma unroll
  for(int rr=0;rr<8;rr++){
    int k1  = lane + 64*rr;
    int k1p = (myc==0) ? ((512-k1)&511) : (511-k1);
    float cr = Cre[k1], ci = Cim[k1];
    float qr = Pre[k1p], qi = -Pim[k1p];          // conj(C[N-k])
    float zur = 0.5f*(cr+qr), zui = 0.5f*(ci+qi);
    float dr = cr-qr, di = ci-qi;
    float tfr = 0.5f*di, tfi = -0.5f*dr;
    float szr = s*zur, szi = s*zui;
    float ntr = fmaf(gs0, szr, tfr), nti = fmaf(gs0, szi, tfi);
    pv0[rr].x = (ntr*szr + nti*szi)*al0;
    pv0[rr].y = (nti*szr - ntr*szi)*al0;
  }
  __syncthreads();   // b0 reads complete before overwrite

  // row b1: forward + Hermitian product
  {
    const float4* c4 = (const float4*)colp1;
    #pragma unroll
    for(int r=0;r<4;r++){
      float4 q = c4[lane + 64*r];
      int j = 2*(lane + 64*r);
      Cre[j]=q.x;   Cim[j]=q.y;
      Cre[j+1]=q.z; Cim[j+1]=q.w;
    }
  }
  wsync();
  fft512_wave<-1>(Cre, Cim, lane, twc, tws);
  __syncthreads();   // partner b1 spectrum ready
  #pragma unroll
  for(int rr=0;rr<8;rr++){
    int k1  = lane + 64*rr;
    int k1p = (myc==0) ? ((512-k1)&511) : (511-k1);
    float cr = Cre[k1], ci = Cim[k1];
    float qr = Pre[k1p], qi = -Pim[k1p];
    float zur = 0.5f*(cr+qr), zui = 0.5f*(ci+qi);
    float dr = cr-qr, di = ci-qi;
    float tfr = 0.5f*di, tfi = -0.5f*dr;
    float szr = s*zur, szi = s*zui;
    float ntr = fmaf(gs1, szr, tfr), nti = fmaf(gs1, szi, tfi);
    pv1[rr].x = (ntr*szr + nti*szi)*al1;
    pv1[rr].y = (nti*szr - ntr*szi)*al1;
  }
  __syncthreads();   // b1 reads complete before overwrite

  // combine G = R_b0 + i*R_b1, one inverse FFT-512
  #pragma unroll
  for(int rr=0;rr<8;rr++){
    int k1 = lane + 64*rr;
    Cre[k1] = pv0[rr].x - pv1[rr].y;
    Cim[k1] = pv0[rr].y + pv1[rr].x;
  }
  wsync();
  fft512_wave<1>(Cre, Cim, lane, twc, tws);
  cf w, st;
  {
    float sv,cv;
    __sincosf(4.793689960382698e-05f * (float)(lane*myc), &sv, &cv);
    w = {cv, sv};
    __sincosf(4.793689960382698e-05f * 64.f * (float)myc, &sv, &cv);
    st = {cv, sv};
  }
  #pragma unroll
  for(int rr=0;rr<8;rr++){
    int m1 = lane + 64*rr;
    cf r2 = cmul(cf{Cre[m1],Cim[m1]}, w);
    colp0[m1] = make_float2(r2.x, r2.y);
    w = cmul(w, st);
  }
}

// ---------------- K4: inverse stage-2 (IFFT-256 over k2), writes TWO rows ----------------
__global__ __launch_bounds__(256) void k4_inv2(
    const float2* __restrict__ Qws, float* __restrict__ dout, int cplx)
{
  __shared__ float reb[4384], imb[4384];
  __shared__ float twc[256], tws[256];
  int t = threadIdx.x;
  int bp = blockIdx.x >> 5;                 // row pair 0..31
  int m1b = (blockIdx.x & 31) << 4;
  int b0 = bp*2;
  {
    float sv, cv;
    __sincosf(0.0245436926061703f * (float)t, &sv, &cv); // +2*pi/256 * t
    twc[t]=cv; tws[t]=sv;
  }
  const float4* Qp = (const float4*)(Qws + ((size_t)b0<<17));
  #pragma unroll
  for(int it=0; it<8; ++it){
    int e = t + 256*it;
    int k2 = e >> 3, j = e & 7;
    float4 q = Qp[k2*256 + (m1b>>1) + j];
    int lb = k2*17 + 2*j;
    reb[lb+0]=q.x; imb[lb+0]=q.y;
    reb[lb+1]=q.z; imb[lb+1]=q.w;
  }
  __syncthreads();
  int f = t & 15, p = t >> 4;
  cf v[16];
  #pragma unroll
  for(int q=0;q<16;q++){ int k2=q*16+p; v[q].x=reb[k2*17+f]; v[q].y=imb[k2*17+f]; }
  fft16<1>(v);
  #pragma unroll
  for(int kq=1;kq<16;kq++){ int tt=(p*kq)&255; v[kq]=cmul(v[kq], cf{twc[tt], tws[tt]}); }
  __syncthreads();
  #pragma unroll
  for(int kq=0;kq<16;kq++){ reb[f*274+kq*17+p]=v[kq].x; imb[f*274+kq*17+p]=v[kq].y; }
  __syncthreads();
  #pragma unroll
  for(int pp=0;pp<16;pp++){ v[pp].x=reb[f*274+p*17+pp]; v[pp].y=imb[f*274+p*17+pp]; }
  fft16<1>(v);
  #pragma unroll
  for(int kp=0;kp<16;kp++){
    int m2 = kp*16 + p;
    size_t n = (size_t)(m1b + f) + (size_t)512*m2;
    size_t o0 = (size_t)b0*DIM + n;        // y.x -> read[b0], y.y -> read[b0+1]
    if(cplx==2){
      ((float2*)dout)[o0]       = make_float2(v[kp].x, 0.f);
      ((float2*)dout)[o0 + DIM] = make_float2(v[kp].y, 0.f);
    } else {
      dout[o0]       = v[kp].x;
      dout[o0 + DIM] = v[kp].y;
    }
  }
}

// ---------------- launch: 4 nodes ----------------
extern "C" void kernel_launch(void* const* d_in, const int* in_sizes, int n_in,
                              void* d_out, int out_size, void* d_ws, size_t ws_size,
                              hipStream_t stream)
{
  (void)in_sizes; (void)n_in; (void)ws_size;
  const float* z    = (const float*)d_in[0];
  const float* tr   = (const float*)d_in[1];
  const float* ctrl = (const float*)d_in[2];
  float* dout = (float*)d_out;
  // complex64 outputs flattened as interleaved float32 -> out_size = 2*2*B*DIM + B + 1.
  int cplx = (out_size > 20000000) ? 2 : 1;
  float* wsmax = (float*)d_ws;                   // 1024 per-block max slots
  float2* Bws = (float2*)((char*)d_ws + 8192);   // 64 MiB intermediate, in-place through K3

  hipLaunchKernelGGL(k1_maxabs,dim3(1024), dim3(256), 0, stream, z, wsmax, dout, cplx);
  hipLaunchKernelGGL(k2_fwd1,  dim3(2048), dim3(256), 0, stream,
                     z, tr, ctrl, wsmax, Bws, dout + (size_t)NROW*DIM*cplx, cplx);
  hipLaunchKernelGGL(k3_mid,   dim3(4096), dim3(128), 0, stream, Bws, ctrl, wsmax);
  hipLaunchKernelGGL(k4_inv2,  dim3(1024), dim3(256), 0, stream, Bws, dout, cplx);
}